// Round 1
// baseline (487.062 us; speedup 1.0000x reference)
//
#include <hip/hip_runtime.h>
#include <math.h>

// AttentionPooling: B=32 S=4096 E=1024 H=16 D=64
// Key transform: k/v projections eliminated by linearity:
//   scores[b,h,s] = (Wk_h^T q[b,h]) . x[b,s] / sqrt(D)
//   ctx[b,h]      = Wv_h (sum_s attn x[b,s]) + bv_h   (sum attn = 1)
// -> two streaming passes over x (memory-bound) instead of two 275-GFLOP GEMMs.

constexpr int cB = 32, cS = 4096, cE = 1024, cH = 16, cD = 64, cNC = 16;

// ws layout in floats
constexpr size_t OFF_P    = 0;                     // B*H*E   = 524288
constexpr size_t OFF_C    = OFF_P + 524288;        // B*H     = 512
constexpr size_t OFF_Q    = OFF_C + 512;           // B*E     = 32768
constexpr size_t OFF_SC   = OFF_Q + 32768;         // B*H*S   = 2097152 (scores, attn in-place)
constexpr size_t OFF_AT   = OFF_SC + 2097152;      // B*S*H   = 2097152 (attn transposed)
constexpr size_t OFF_Y    = OFF_AT + 2097152;      // B*H*E   = 524288
constexpr size_t OFF_CTX  = OFF_Y + 524288;        // B*E     = 32768
constexpr size_t OFF_PART = OFF_CTX + 32768;       // B*NC*H*E = 8388608
// total = 13,697,536 floats = 54.8 MB

__device__ inline float wave_max64(float v) {
#pragma unroll
  for (int m = 1; m < 64; m <<= 1) v = fmaxf(v, __shfl_xor(v, m));
  return v;
}
__device__ inline float wave_sum64(float v) {
#pragma unroll
  for (int m = 1; m < 64; m <<= 1) v += __shfl_xor(v, m);
  return v;
}

// ---------------- Kernel 1a: q[b,:] = Wq @ x[b,0,:] + bq ----------------
// grid 256 = B*8, block 256. Each block: 128 q-rows, 2 threads/row (K-split).
__global__ __launch_bounds__(256) void k1a_q(const float* __restrict__ x,
                                             const float* __restrict__ w,   // in_proj_w (3E x E)
                                             const float* __restrict__ bias,// in_proj_b (3E)
                                             float* __restrict__ q) {
  int b = blockIdx.x >> 3, blk = blockIdx.x & 7;
  int tid = threadIdx.x;
  __shared__ float x0[cE];
  ((float4*)x0)[tid] = ((const float4*)(x + (size_t)b * cS * cE))[tid];
  __syncthreads();
  int row = blk * 128 + (tid >> 1);
  int half = tid & 1;
  const float* wr = w + (size_t)row * cE + half * 512;
  const float* xl = x0 + half * 512;
  float acc = 0.f;
#pragma unroll 4
  for (int j = 0; j < 128; ++j) {
    float4 a = *(const float4*)(wr + j * 4);
    float4 xv = *(const float4*)(xl + j * 4);
    acc = fmaf(a.x, xv.x, acc); acc = fmaf(a.y, xv.y, acc);
    acc = fmaf(a.z, xv.z, acc); acc = fmaf(a.w, xv.w, acc);
  }
  float tot = acc + __shfl_xor(acc, 1);
  if (!half) q[b * cE + row] = tot + bias[row];
}

// ---------------- Kernel 1b: p[b,h,:] = 0.125 * Wk_h^T q[b,h]; c[b,h] = 0.125*q.bk_h ----
// grid B, block 256. Thread owns 4 consecutive e-columns; Wk rows streamed coalesced.
__global__ __launch_bounds__(256) void k1b_p(const float* __restrict__ w,
                                             const float* __restrict__ bvec,
                                             const float* __restrict__ q,
                                             float* __restrict__ p,
                                             float* __restrict__ cb) {
  int b = blockIdx.x;
  int tid = threadIdx.x;
  __shared__ float ql[cE];
  ((float4*)ql)[tid] = ((const float4*)(q + (size_t)b * cE))[tid];
  __syncthreads();
  int e0 = tid * 4;
  for (int h = 0; h < cH; ++h) {
    float a0 = 0, a1 = 0, a2 = 0, a3 = 0;
    const float* wb = w + (size_t)(cE + h * cD) * cE + e0;
#pragma unroll 4
    for (int d = 0; d < cD; ++d) {
      float qv = ql[h * cD + d];
      float4 wv = *(const float4*)(wb + (size_t)d * cE);
      a0 = fmaf(wv.x, qv, a0); a1 = fmaf(wv.y, qv, a1);
      a2 = fmaf(wv.z, qv, a2); a3 = fmaf(wv.w, qv, a3);
    }
    float4 o = make_float4(a0 * 0.125f, a1 * 0.125f, a2 * 0.125f, a3 * 0.125f);
    *(float4*)(p + (size_t)(b * cH + h) * cE + e0) = o;
  }
  if (tid < cH) {
    int h = tid;
    float cacc = 0.f;
    for (int d = 0; d < cD; ++d) cacc = fmaf(ql[h * cD + d], bvec[cE + h * cD + d], cacc);
    cb[b * cH + h] = 0.125f * cacc;
  }
}

// ---------------- Kernel 2: scores[b,h,s] = p[b,h,:] . x[b,s,:] + c[b,h] ----------------
// grid 512 = B*16 s-chunks of 256, block 256 (64 s-threads x 4 h-threads, tile 4s x 4h).
// x tile staged transposed [e][s] with XOR swizzle: compute reads are contiguous 1024B
// wave reads (conflict-free); p reads are same-address broadcasts.
__global__ __launch_bounds__(256) void k2_scores(const float* __restrict__ x,
                                                 const float* __restrict__ p,
                                                 const float* __restrict__ cbias,
                                                 float* __restrict__ scores) {
  __shared__ float xT[32 * 256];   // [e][swizzled s], 32 KB
  __shared__ float pT[32 * 16];    // [e][h], 2 KB
  int bx = blockIdx.x;
  int b = bx >> 4, sc = bx & 15;
  int s_base = sc * 256;
  int tid = threadIdx.x;
  int s_t = tid & 63, h_t = tid >> 6;
  int h0 = h_t * 4;
  float acc[4][4];
#pragma unroll
  for (int i = 0; i < 4; ++i)
#pragma unroll
    for (int j = 0; j < 4; ++j) acc[i][j] = 0.f;

  const float* xb = x + ((size_t)b * cS + s_base) * cE;

  for (int kt = 0; kt < 32; ++kt) {
    // stage x tile transposed+swizzled
#pragma unroll
    for (int i = 0; i < 8; ++i) {
      int f4i = i * 256 + tid;
      int r = f4i >> 3, c4 = f4i & 7;
      float4 v = *(const float4*)(xb + (size_t)r * cE + kt * 32 + c4 * 4);
      float vv[4] = {v.x, v.y, v.z, v.w};
#pragma unroll
      for (int j = 0; j < 4; ++j) {
        int e = c4 * 4 + j;
        int f = (e ^ (e >> 4)) & 15;
        xT[e * 256 + ((((r >> 2) ^ f) << 2) | (r & 3))] = vv[j];
      }
    }
    // stage p tile [e][h]
#pragma unroll
    for (int k2 = 0; k2 < 2; ++k2) {
      int ii = k2 * 256 + tid;
      int h = ii >> 5, e = ii & 31;
      pT[e * 16 + h] = p[(size_t)(b * cH + h) * cE + kt * 32 + e];
    }
    __syncthreads();
#pragma unroll 8
    for (int e = 0; e < 32; ++e) {
      int f = (e ^ (e >> 4)) & 15;
      float4 xv = *(const float4*)&xT[e * 256 + ((s_t ^ f) << 2)];
      float4 pv = *(const float4*)&pT[e * 16 + h0];
      float xa[4] = {xv.x, xv.y, xv.z, xv.w};
      float pa[4] = {pv.x, pv.y, pv.z, pv.w};
#pragma unroll
      for (int si = 0; si < 4; ++si)
#pragma unroll
        for (int hj = 0; hj < 4; ++hj) acc[si][hj] = fmaf(xa[si], pa[hj], acc[si][hj]);
    }
    __syncthreads();
  }
  float4 cv = *(const float4*)(cbias + b * cH + h0);
  float ca[4] = {cv.x, cv.y, cv.z, cv.w};
#pragma unroll
  for (int hj = 0; hj < 4; ++hj) {
    float4 o = make_float4(acc[0][hj] + ca[hj], acc[1][hj] + ca[hj],
                           acc[2][hj] + ca[hj], acc[3][hj] + ca[hj]);
    *(float4*)(scores + (size_t)(b * cH + h0 + hj) * cS + s_base + s_t * 4) = o;
  }
}

// ---------------- Kernel 3a: masked softmax in-place over s (per b,h row) ----------------
__global__ __launch_bounds__(256) void k3a_softmax(float* __restrict__ scores,
                                                   const int* __restrict__ mask) {
  int b = blockIdx.x >> 4, h = blockIdx.x & 15;
  float* row = scores + (size_t)(b * cH + h) * cS;
  const int* mrow = mask + b * cS;
  int tid = threadIdx.x;
  __shared__ float sm[4], ss[4];
  float v[16];
#pragma unroll
  for (int k = 0; k < 4; ++k) {
    int i4 = k * 256 + tid;
    float4 vv = *(const float4*)(row + (size_t)i4 * 4);
    int4 m4 = *(const int4*)(mrow + (size_t)i4 * 4);
    v[k * 4 + 0] = m4.x ? -1e30f : vv.x;
    v[k * 4 + 1] = m4.y ? -1e30f : vv.y;
    v[k * 4 + 2] = m4.z ? -1e30f : vv.z;
    v[k * 4 + 3] = m4.w ? -1e30f : vv.w;
  }
  float mx = v[0];
#pragma unroll
  for (int i = 1; i < 16; ++i) mx = fmaxf(mx, v[i]);
  mx = wave_max64(mx);
  if ((tid & 63) == 0) sm[tid >> 6] = mx;
  __syncthreads();
  float M = fmaxf(fmaxf(sm[0], sm[1]), fmaxf(sm[2], sm[3]));
  float ex[16];
  float lsum = 0.f;
#pragma unroll
  for (int i = 0; i < 16; ++i) { ex[i] = __expf(v[i] - M); lsum += ex[i]; }
  lsum = wave_sum64(lsum);
  if ((tid & 63) == 0) ss[tid >> 6] = lsum;
  __syncthreads();
  float L = ss[0] + ss[1] + ss[2] + ss[3];
  float inv = 1.0f / L;
#pragma unroll
  for (int k = 0; k < 4; ++k) {
    int i4 = k * 256 + tid;
    float4 o = make_float4(ex[k * 4 + 0] * inv, ex[k * 4 + 1] * inv,
                           ex[k * 4 + 2] * inv, ex[k * 4 + 3] * inv);
    *(float4*)(row + (size_t)i4 * 4) = o;
  }
}

// ---------------- Kernel 3b: attn_weights = mean_h attn; attn_T[b][s][h] ----------------
__global__ __launch_bounds__(256) void k3b_mean_t(const float* __restrict__ attn,
                                                  float* __restrict__ attnT,
                                                  float* __restrict__ out) {
  int idx = blockIdx.x * 256 + threadIdx.x;
  int b = idx >> 12, s = idx & 4095;
  float a[16];
  float sum = 0.f;
#pragma unroll
  for (int h = 0; h < cH; ++h) {
    a[h] = attn[(size_t)(b * cH + h) * cS + s];
    sum += a[h];
  }
  out[32768 + (size_t)b * cS + s] = sum * (1.0f / 16.0f);
  float4* dst = (float4*)(attnT + (size_t)(b * cS + s) * cH);
  dst[0] = make_float4(a[0], a[1], a[2], a[3]);
  dst[1] = make_float4(a[4], a[5], a[6], a[7]);
  dst[2] = make_float4(a[8], a[9], a[10], a[11]);
  dst[3] = make_float4(a[12], a[13], a[14], a[15]);
}

// ---------------- Kernel 4: part[b,sc,h,e] = sum_{s in chunk} attn[b,h,s]*x[b,s,e] ------
// grid 1024 = B * NC * 2 e-halves, block 256; thread owns 2 e x 16 h; attn via uniform loads.
__global__ __launch_bounds__(256) void k4_wsum(const float* __restrict__ x,
                                               const float* __restrict__ attnT,
                                               float* __restrict__ part) {
  int bx = blockIdx.x;
  int b = bx >> 5, rest = bx & 31;
  int sc = rest >> 1, eh = rest & 1;
  int tid = threadIdx.x;
  int e0 = eh * 512 + tid * 2;
  float2 acc[16];
#pragma unroll
  for (int h = 0; h < cH; ++h) acc[h] = make_float2(0.f, 0.f);
  const float* xb = x + ((size_t)b * cS + sc * 256) * cE + e0;
  const float* aT = attnT + ((size_t)b * cS + sc * 256) * cH;
#pragma unroll 2
  for (int s = 0; s < 256; ++s) {
    const float4* a4 = (const float4*)(aT + s * 16);
    float4 a0 = a4[0], a1 = a4[1], a2 = a4[2], a3 = a4[3];
    float2 xv = *(const float2*)(xb + (size_t)s * cE);
    float aa[16] = {a0.x, a0.y, a0.z, a0.w, a1.x, a1.y, a1.z, a1.w,
                    a2.x, a2.y, a2.z, a2.w, a3.x, a3.y, a3.z, a3.w};
#pragma unroll
    for (int h = 0; h < cH; ++h) {
      acc[h].x = fmaf(aa[h], xv.x, acc[h].x);
      acc[h].y = fmaf(aa[h], xv.y, acc[h].y);
    }
  }
  float* pb = part + ((size_t)(b * cNC + sc) * cH) * cE + e0;
#pragma unroll
  for (int h = 0; h < cH; ++h) *(float2*)(pb + (size_t)h * cE) = acc[h];
}

// ---------------- Kernel 5a: y[b,h,e] = sum_sc part ----------------
__global__ __launch_bounds__(256) void k5a_red(const float* __restrict__ part,
                                               float* __restrict__ y) {
  int g = blockIdx.x * 256 + threadIdx.x;  // float4 index over B*H*E/4
  int bh = g >> 8, e4 = g & 255;
  int b = bh >> 4, h = bh & 15;
  float4 acc = make_float4(0.f, 0.f, 0.f, 0.f);
#pragma unroll
  for (int sc = 0; sc < cNC; ++sc) {
    float4 v = *(const float4*)(part + ((size_t)(b * cNC + sc) * cH + h) * cE + e4 * 4);
    acc.x += v.x; acc.y += v.y; acc.z += v.z; acc.w += v.w;
  }
  *(float4*)(y + (size_t)bh * cE + e4 * 4) = acc;
}

// ---------------- Kernel 5b: ctx[b, h*64+d] = Wv_h[d,:] . y[b,h,:] + bv ----------------
__global__ __launch_bounds__(256) void k5b_ctx(const float* __restrict__ w,
                                               const float* __restrict__ bvec,
                                               const float* __restrict__ y,
                                               float* __restrict__ ctx) {
  int b = blockIdx.x >> 4, h = blockIdx.x & 15;
  int tid = threadIdx.x;
  __shared__ float yl[cE];
  ((float4*)yl)[tid] = ((const float4*)(y + (size_t)(b * cH + h) * cE))[tid];
  __syncthreads();
  int wid = tid >> 6, lane = tid & 63;
  for (int i = 0; i < 16; ++i) {
    int d = wid * 16 + i;
    const float* wr = w + (size_t)(2 * cE + h * cD + d) * cE + lane * 16;
    const float* yr = yl + lane * 16;
    float partial = 0.f;
#pragma unroll
    for (int j = 0; j < 4; ++j) {
      float4 wv = *(const float4*)(wr + j * 4);
      float4 yv = *(const float4*)(yr + j * 4);
      partial = fmaf(wv.x, yv.x, partial); partial = fmaf(wv.y, yv.y, partial);
      partial = fmaf(wv.z, yv.z, partial); partial = fmaf(wv.w, yv.w, partial);
    }
    partial = wave_sum64(partial);
    if (lane == 0) ctx[b * cE + h * cD + d] = partial + bvec[2 * cE + h * cD + d];
  }
}

// ---------------- Kernel 5c: out[b,:] = out_w @ ctx[b,:] + out_b ----------------
__global__ __launch_bounds__(256) void k5c_out(const float* __restrict__ w,
                                               const float* __restrict__ bvec,
                                               const float* __restrict__ ctx,
                                               float* __restrict__ out) {
  int b = blockIdx.x >> 3, br = blockIdx.x & 7;
  int tid = threadIdx.x;
  __shared__ float cl[cE];
  ((float4*)cl)[tid] = ((const float4*)(ctx + (size_t)b * cE))[tid];
  __syncthreads();
  int wid = tid >> 6, lane = tid & 63;
  for (int i = 0; i < 32; ++i) {
    int row = br * 128 + wid * 32 + i;
    const float* wr = w + (size_t)row * cE + lane * 16;
    const float* cr = cl + lane * 16;
    float partial = 0.f;
#pragma unroll
    for (int j = 0; j < 4; ++j) {
      float4 wv = *(const float4*)(wr + j * 4);
      float4 cv = *(const float4*)(cr + j * 4);
      partial = fmaf(wv.x, cv.x, partial); partial = fmaf(wv.y, cv.y, partial);
      partial = fmaf(wv.z, cv.z, partial); partial = fmaf(wv.w, cv.w, partial);
    }
    partial = wave_sum64(partial);
    if (lane == 0) out[(size_t)b * cE + row] = partial + bvec[row];
  }
}

extern "C" void kernel_launch(void* const* d_in, const int* in_sizes, int n_in,
                              void* d_out, int out_size, void* d_ws, size_t ws_size,
                              hipStream_t stream) {
  const float* x = (const float*)d_in[0];
  const int* mask = (const int*)d_in[1];
  const float* in_proj_w = (const float*)d_in[2];
  const float* in_proj_b = (const float*)d_in[3];
  const float* out_w = (const float*)d_in[4];
  const float* out_b = (const float*)d_in[5];
  float* out = (float*)d_out;
  float* W = (float*)d_ws;

  float* p = W + OFF_P;
  float* cb = W + OFF_C;
  float* q = W + OFF_Q;
  float* scores = W + OFF_SC;   // becomes attn in-place
  float* attnT = W + OFF_AT;
  float* y = W + OFF_Y;
  float* ctx = W + OFF_CTX;
  float* part = W + OFF_PART;

  k1a_q<<<256, 256, 0, stream>>>(x, in_proj_w, in_proj_b, q);
  k1b_p<<<32, 256, 0, stream>>>(in_proj_w, in_proj_b, q, p, cb);
  k2_scores<<<512, 256, 0, stream>>>(x, p, cb, scores);
  k3a_softmax<<<512, 256, 0, stream>>>(scores, mask);
  k3b_mean_t<<<512, 256, 0, stream>>>(scores, attnT, out);
  k4_wsum<<<1024, 256, 0, stream>>>(x, attnT, part);
  k5a_red<<<512, 256, 0, stream>>>(part, y);
  k5b_ctx<<<512, 256, 0, stream>>>(in_proj_w, in_proj_b, y, ctx);
  k5c_out<<<256, 256, 0, stream>>>(out_w, out_b, ctx, out);
}

// Round 2
// 409.701 us; speedup vs baseline: 1.1888x; 1.1888x over previous
//
#include <hip/hip_runtime.h>
#include <math.h>

// AttentionPooling: B=32 S=4096 E=1024 H=16 D=64
// scores[b,h,s] = (Wk_h^T q[b,h]) . x[b,s] / 8  ;  ctx[b,h] = Wv_h (sum_s attn x[b,s]) + bv
// Two streaming passes over x (k2 scores, k4 weighted sum); everything else is small.

constexpr int cB = 32, cS = 4096, cE = 1024, cH = 16, cD = 64, cNC = 16;

// ws layout in floats
constexpr size_t OFF_P    = 0;                     // B*H*E   = 524288
constexpr size_t OFF_C    = OFF_P + 524288;        // B*H     = 512
constexpr size_t OFF_Q    = OFF_C + 512;           // B*E     = 32768
constexpr size_t OFF_SC   = OFF_Q + 32768;         // B*H*S   = 2097152 (scores -> attn in place)
constexpr size_t OFF_CTX  = OFF_SC + 2097152;      // B*E     = 32768
constexpr size_t OFF_PART = OFF_CTX + 32768;       // B*NC*H*E = 8388608

__device__ inline float wave_max64(float v) {
#pragma unroll
  for (int m = 1; m < 64; m <<= 1) v = fmaxf(v, __shfl_xor(v, m));
  return v;
}
__device__ inline float wave_sum64(float v) {
#pragma unroll
  for (int m = 1; m < 64; m <<= 1) v += __shfl_xor(v, m);
  return v;
}

// ---------------- Kernel 1a: q[b,:] = Wq @ x[b,0,:] + bq ----------------
__global__ __launch_bounds__(256) void k1a_q(const float* __restrict__ x,
                                             const float* __restrict__ w,
                                             const float* __restrict__ bias,
                                             float* __restrict__ q) {
  int b = blockIdx.x >> 3, blk = blockIdx.x & 7;
  int tid = threadIdx.x;
  __shared__ float x0[cE];
  ((float4*)x0)[tid] = ((const float4*)(x + (size_t)b * cS * cE))[tid];
  __syncthreads();
  int row = blk * 128 + (tid >> 1);
  int half = tid & 1;
  const float* wr = w + (size_t)row * cE + half * 512;
  const float* xl = x0 + half * 512;
  float acc = 0.f;
#pragma unroll 4
  for (int j = 0; j < 128; ++j) {
    float4 a = *(const float4*)(wr + j * 4);
    float4 xv = *(const float4*)(xl + j * 4);
    acc = fmaf(a.x, xv.x, acc); acc = fmaf(a.y, xv.y, acc);
    acc = fmaf(a.z, xv.z, acc); acc = fmaf(a.w, xv.w, acc);
  }
  float tot = acc + __shfl_xor(acc, 1);
  if (!half) q[b * cE + row] = tot + bias[row];
}

// ---------------- Kernel 1b: p[b,h,e] = 0.125 * sum_d Wk[h*64+d, e] q[b, h*64+d] ------
// grid 128 = 32 b x 4 e-chunks of 256. Thread owns one e column.
__global__ __launch_bounds__(256) void k1b_p(const float* __restrict__ w,
                                             const float* __restrict__ bvec,
                                             const float* __restrict__ q,
                                             float* __restrict__ p,
                                             float* __restrict__ cb) {
  int b = blockIdx.x >> 2, ec = blockIdx.x & 3;
  int tid = threadIdx.x;
  int e = ec * 256 + tid;
  __shared__ float ql[cE];
  ((float4*)ql)[tid] = ((const float4*)(q + (size_t)b * cE))[tid];
  __syncthreads();
  for (int h = 0; h < cH; ++h) {
    float acc = 0.f;
    const float* wb = w + (size_t)(cE + h * cD) * cE + e;
    const float* qh = ql + h * cD;
#pragma unroll 8
    for (int d = 0; d < cD; ++d) acc = fmaf(wb[(size_t)d * cE], qh[d], acc);
    p[(size_t)(b * cH + h) * cE + e] = 0.125f * acc;
  }
  if (ec == 0 && tid < cH) {
    int h = tid;
    float cacc = 0.f;
    for (int d = 0; d < cD; ++d) cacc = fmaf(ql[h * cD + d], bvec[cE + h * cD + d], cacc);
    cb[b * cH + h] = 0.125f * cacc;
  }
}

// ---------------- Kernel 2: scores[b,h,s] = p[b,h,:] . x[b,s,:] + c[b,h] ----------------
// grid 512 = B*16 s-chunks of 256, block 256 (64 s-threads x 4 h-waves, tile 4s x 4h).
// Double-buffered LDS; T14 split: issue next-tile global loads, compute, then ds_write.
__global__ __launch_bounds__(256) void k2_scores(const float* __restrict__ x,
                                                 const float* __restrict__ p,
                                                 const float* __restrict__ cbias,
                                                 float* __restrict__ scores) {
  __shared__ float xT[2][32 * 256];   // [buf][e][swizzled s], 2x32 KB
  __shared__ float pT[2][32 * 16];    // [buf][e][h]
  int bx = blockIdx.x;
  int b = bx >> 4, sc = bx & 15;
  int s_base = sc * 256;
  int tid = threadIdx.x;
  int s_t = tid & 63, h_t = tid >> 6;
  int h0 = h_t * 4;
  float acc[4][4];
#pragma unroll
  for (int i = 0; i < 4; ++i)
#pragma unroll
    for (int j = 0; j < 4; ++j) acc[i][j] = 0.f;

  const float* xb = x + ((size_t)b * cS + s_base) * cE;

  float4 sv[8];
  float pv0, pv1;
  int r_ = tid >> 3, c4_ = tid & 7;           // staging coords (per i: r = r_ + i*32)
  int ph0 = tid >> 5, pe0 = tid & 31;         // p staging coords

  // prologue: stage kt=0
#pragma unroll
  for (int i = 0; i < 8; ++i)
    sv[i] = *(const float4*)(xb + (size_t)(i * 32 + r_) * cE + c4_ * 4);
  pv0 = p[(size_t)(b * cH + ph0) * cE + pe0];
  pv1 = p[(size_t)(b * cH + ph0 + 8) * cE + pe0];
  {
    float* xd = xT[0]; float* pd = pT[0];
#pragma unroll
    for (int i = 0; i < 8; ++i) {
      int r = i * 32 + r_;
      float vv[4] = {sv[i].x, sv[i].y, sv[i].z, sv[i].w};
#pragma unroll
      for (int j = 0; j < 4; ++j) {
        int e = c4_ * 4 + j;
        int f = (e ^ (e >> 4)) & 15;
        xd[e * 256 + ((((r >> 2) ^ f) << 2) | (r & 3))] = vv[j];
      }
    }
    pd[pe0 * 16 + ph0] = pv0;
    pd[pe0 * 16 + ph0 + 8] = pv1;
  }
  __syncthreads();

  for (int kt = 1; kt <= 32; ++kt) {
    if (kt < 32) {
      // early-issue next tile's global loads
#pragma unroll
      for (int i = 0; i < 8; ++i)
        sv[i] = *(const float4*)(xb + (size_t)(i * 32 + r_) * cE + kt * 32 + c4_ * 4);
      pv0 = p[(size_t)(b * cH + ph0) * cE + kt * 32 + pe0];
      pv1 = p[(size_t)(b * cH + ph0 + 8) * cE + kt * 32 + pe0];
    }
    // compute on previous buffer (hides the loads above)
    {
      const float* xs = xT[(kt - 1) & 1];
      const float* ps = pT[(kt - 1) & 1];
#pragma unroll 8
      for (int e = 0; e < 32; ++e) {
        int f = (e ^ (e >> 4)) & 15;
        float4 xv = *(const float4*)&xs[e * 256 + ((s_t ^ f) << 2)];
        float4 pvv = *(const float4*)&ps[e * 16 + h0];
        float xa[4] = {xv.x, xv.y, xv.z, xv.w};
        float pa[4] = {pvv.x, pvv.y, pvv.z, pvv.w};
#pragma unroll
        for (int si = 0; si < 4; ++si)
#pragma unroll
          for (int hj = 0; hj < 4; ++hj) acc[si][hj] = fmaf(xa[si], pa[hj], acc[si][hj]);
      }
    }
    if (kt < 32) {
      float* xd = xT[kt & 1]; float* pd = pT[kt & 1];
#pragma unroll
      for (int i = 0; i < 8; ++i) {
        int r = i * 32 + r_;
        float vv[4] = {sv[i].x, sv[i].y, sv[i].z, sv[i].w};
#pragma unroll
        for (int j = 0; j < 4; ++j) {
          int e = c4_ * 4 + j;
          int f = (e ^ (e >> 4)) & 15;
          xd[e * 256 + ((((r >> 2) ^ f) << 2) | (r & 3))] = vv[j];
        }
      }
      pd[pe0 * 16 + ph0] = pv0;
      pd[pe0 * 16 + ph0 + 8] = pv1;
    }
    __syncthreads();
  }

  float4 cv = *(const float4*)(cbias + b * cH + h0);
  float ca[4] = {cv.x, cv.y, cv.z, cv.w};
#pragma unroll
  for (int hj = 0; hj < 4; ++hj) {
    float4 o = make_float4(acc[0][hj] + ca[hj], acc[1][hj] + ca[hj],
                           acc[2][hj] + ca[hj], acc[3][hj] + ca[hj]);
    *(float4*)(scores + (size_t)(b * cH + h0 + hj) * cS + s_base + s_t * 4) = o;
  }
}

// ---------------- Kernel 3: masked softmax in-place over s (per b,h row) ----------------
__global__ __launch_bounds__(256) void k3a_softmax(float* __restrict__ scores,
                                                   const int* __restrict__ mask) {
  int b = blockIdx.x >> 4, h = blockIdx.x & 15;
  float* row = scores + (size_t)(b * cH + h) * cS;
  const int* mrow = mask + b * cS;
  int tid = threadIdx.x;
  __shared__ float sm[4], ss[4];
  float v[16];
#pragma unroll
  for (int k = 0; k < 4; ++k) {
    int i4 = k * 256 + tid;
    float4 vv = *(const float4*)(row + (size_t)i4 * 4);
    int4 m4 = *(const int4*)(mrow + (size_t)i4 * 4);
    v[k * 4 + 0] = m4.x ? -1e30f : vv.x;
    v[k * 4 + 1] = m4.y ? -1e30f : vv.y;
    v[k * 4 + 2] = m4.z ? -1e30f : vv.z;
    v[k * 4 + 3] = m4.w ? -1e30f : vv.w;
  }
  float mx = v[0];
#pragma unroll
  for (int i = 1; i < 16; ++i) mx = fmaxf(mx, v[i]);
  mx = wave_max64(mx);
  if ((tid & 63) == 0) sm[tid >> 6] = mx;
  __syncthreads();
  float M = fmaxf(fmaxf(sm[0], sm[1]), fmaxf(sm[2], sm[3]));
  float ex[16];
  float lsum = 0.f;
#pragma unroll
  for (int i = 0; i < 16; ++i) { ex[i] = __expf(v[i] - M); lsum += ex[i]; }
  lsum = wave_sum64(lsum);
  if ((tid & 63) == 0) ss[tid >> 6] = lsum;
  __syncthreads();
  float L = ss[0] + ss[1] + ss[2] + ss[3];
  float inv = 1.0f / L;
#pragma unroll
  for (int k = 0; k < 4; ++k) {
    int i4 = k * 256 + tid;
    float4 o = make_float4(ex[k * 4 + 0] * inv, ex[k * 4 + 1] * inv,
                           ex[k * 4 + 2] * inv, ex[k * 4 + 3] * inv);
    *(float4*)(row + (size_t)i4 * 4) = o;
  }
}

// ---------------- Kernel 4: part[b,sc,h,e] = sum_s attn[b,h,s]*x[b,s,e]; fused mean ----
// grid 512 = B*16 s-chunks, block 256; thread owns 4 e x 16 h. attn read via uniform
// (scalar) loads; attn_weights mean captured when s == tid.
__global__ __launch_bounds__(256) void k4_wsum(const float* __restrict__ x,
                                               const float* __restrict__ attn,
                                               float* __restrict__ part,
                                               float* __restrict__ out) {
  int bx = blockIdx.x;
  int b = bx >> 4, sc = bx & 15;
  int tid = threadIdx.x;
  int e0 = tid * 4;
  const float* xb = x + ((size_t)b * cS + sc * 256) * cE + e0;
  const float* ab = attn + (size_t)b * cH * cS + sc * 256;
  float4 acc[16];
#pragma unroll
  for (int h = 0; h < cH; ++h) acc[h] = make_float4(0.f, 0.f, 0.f, 0.f);
  float msum = 0.f;
#pragma unroll 2
  for (int s = 0; s < 256; ++s) {
    float4 xv = *(const float4*)(xb + (size_t)s * cE);
    float aa[16];
    float sh = 0.f;
#pragma unroll
    for (int h = 0; h < cH; ++h) { aa[h] = ab[(size_t)h * cS + s]; sh += aa[h]; }
    if (s == tid) msum = sh;
#pragma unroll
    for (int h = 0; h < cH; ++h) {
      acc[h].x = fmaf(aa[h], xv.x, acc[h].x);
      acc[h].y = fmaf(aa[h], xv.y, acc[h].y);
      acc[h].z = fmaf(aa[h], xv.z, acc[h].z);
      acc[h].w = fmaf(aa[h], xv.w, acc[h].w);
    }
  }
  float* pb = part + ((size_t)(b * cNC + sc) * cH) * cE + e0;
#pragma unroll
  for (int h = 0; h < cH; ++h) *(float4*)(pb + (size_t)h * cE) = acc[h];
  out[cB * cE + (size_t)b * cS + sc * 256 + tid] = msum * (1.0f / 16.0f);
}

// ---------------- Kernel 5: y = sum_sc part; ctx[b,h*64+d] = Wv_h[d,:].y + bv ----------
__global__ __launch_bounds__(256) void k5_ctx(const float* __restrict__ w,
                                              const float* __restrict__ bvec,
                                              const float* __restrict__ part,
                                              float* __restrict__ ctx) {
  int b = blockIdx.x >> 4, h = blockIdx.x & 15;
  int tid = threadIdx.x;
  __shared__ float yl[cE];
  float4 a = make_float4(0.f, 0.f, 0.f, 0.f);
  const float* pb = part + ((size_t)(b * cNC) * cH + h) * cE + tid * 4;
#pragma unroll
  for (int s = 0; s < cNC; ++s) {
    float4 v = *(const float4*)(pb + (size_t)s * cH * cE);
    a.x += v.x; a.y += v.y; a.z += v.z; a.w += v.w;
  }
  *(float4*)(yl + tid * 4) = a;
  __syncthreads();
  int wid = tid >> 6, lane = tid & 63;
  for (int i = 0; i < 16; ++i) {
    int d = wid * 16 + i;
    const float* wr = w + (size_t)(2 * cE + h * cD + d) * cE + lane * 16;
    const float* yr = yl + lane * 16;
    float partial = 0.f;
#pragma unroll
    for (int j = 0; j < 4; ++j) {
      float4 wv = *(const float4*)(wr + j * 4);
      float4 yv = *(const float4*)(yr + j * 4);
      partial = fmaf(wv.x, yv.x, partial); partial = fmaf(wv.y, yv.y, partial);
      partial = fmaf(wv.z, yv.z, partial); partial = fmaf(wv.w, yv.w, partial);
    }
    partial = wave_sum64(partial);
    if (lane == 0) ctx[b * cE + h * cD + d] = partial + bvec[2 * cE + h * cD + d];
  }
}

// ---------------- Kernel 6: out[b,:] = out_w @ ctx[b,:] + out_b ----------------
__global__ __launch_bounds__(256) void k6_out(const float* __restrict__ w,
                                              const float* __restrict__ bvec,
                                              const float* __restrict__ ctx,
                                              float* __restrict__ out) {
  int b = blockIdx.x >> 3, br = blockIdx.x & 7;
  int tid = threadIdx.x;
  __shared__ float cl[cE];
  ((float4*)cl)[tid] = ((const float4*)(ctx + (size_t)b * cE))[tid];
  __syncthreads();
  int wid = tid >> 6, lane = tid & 63;
  for (int i = 0; i < 32; ++i) {
    int row = br * 128 + wid * 32 + i;
    const float* wr = w + (size_t)row * cE + lane * 16;
    const float* cr = cl + lane * 16;
    float partial = 0.f;
#pragma unroll
    for (int j = 0; j < 4; ++j) {
      float4 wv = *(const float4*)(wr + j * 4);
      float4 cv = *(const float4*)(cr + j * 4);
      partial = fmaf(wv.x, cv.x, partial); partial = fmaf(wv.y, cv.y, partial);
      partial = fmaf(wv.z, cv.z, partial); partial = fmaf(wv.w, cv.w, partial);
    }
    partial = wave_sum64(partial);
    if (lane == 0) out[(size_t)b * cE + row] = partial + bvec[row];
  }
}

extern "C" void kernel_launch(void* const* d_in, const int* in_sizes, int n_in,
                              void* d_out, int out_size, void* d_ws, size_t ws_size,
                              hipStream_t stream) {
  const float* x = (const float*)d_in[0];
  const int* mask = (const int*)d_in[1];
  const float* in_proj_w = (const float*)d_in[2];
  const float* in_proj_b = (const float*)d_in[3];
  const float* out_w = (const float*)d_in[4];
  const float* out_b = (const float*)d_in[5];
  float* out = (float*)d_out;
  float* W = (float*)d_ws;

  float* p = W + OFF_P;
  float* cb = W + OFF_C;
  float* q = W + OFF_Q;
  float* scores = W + OFF_SC;   // becomes attn in-place
  float* ctx = W + OFF_CTX;
  float* part = W + OFF_PART;

  k1a_q<<<256, 256, 0, stream>>>(x, in_proj_w, in_proj_b, q);
  k1b_p<<<128, 256, 0, stream>>>(in_proj_w, in_proj_b, q, p, cb);
  k2_scores<<<512, 256, 0, stream>>>(x, p, cb, scores);
  k3a_softmax<<<512, 256, 0, stream>>>(scores, mask);
  k4_wsum<<<512, 256, 0, stream>>>(x, scores, part, out);
  k5_ctx<<<512, 256, 0, stream>>>(in_proj_w, in_proj_b, part, ctx);
  k6_out<<<256, 256, 0, stream>>>(out_w, out_b, ctx, out);
}

// Round 3
// 374.764 us; speedup vs baseline: 1.2996x; 1.0932x over previous
//
#include <hip/hip_runtime.h>
#include <math.h>

// AttentionPooling: B=32 S=4096 E=1024 H=16 D=64
// scores[b,h,s] = (Wk_h^T q[b,h]) . x[b,s] / 8 ; ctx[b,h] = Wv_h (sum_s attn x[b,s]) + bv
// Two streaming x-passes (k2 scores+mask+chunk-stats, k4 exp-normalize+weighted-sum).

constexpr int cB = 32, cS = 4096, cE = 1024, cH = 16, cD = 64, cNC = 16;

// ws layout in floats
constexpr size_t OFF_P    = 0;                     // B*H*E   = 524288
constexpr size_t OFF_C    = OFF_P + 524288;        // B*H     = 512
constexpr size_t OFF_Q    = OFF_C + 512;           // B*E     = 32768
constexpr size_t OFF_SC   = OFF_Q + 32768;         // B*H*S   = 2097152 (masked scores)
constexpr size_t OFF_CTX  = OFF_SC + 2097152;      // B*E     = 32768
constexpr size_t OFF_SM   = OFF_CTX + 32768;       // B*H*NC  = 8192 chunk max
constexpr size_t OFF_SL   = OFF_SM + 8192;         // B*H*NC  = 8192 chunk expsum
constexpr size_t OFF_MF   = OFF_SL + 8192;         // B*H     = 512 row max
constexpr size_t OFF_IL   = OFF_MF + 512;          // B*H     = 512 inv rowsum
constexpr size_t OFF_PART = OFF_IL + 512;          // B*NC*H*E = 8388608

__device__ inline float wave_max64(float v) {
#pragma unroll
  for (int m = 1; m < 64; m <<= 1) v = fmaxf(v, __shfl_xor(v, m));
  return v;
}
__device__ inline float wave_sum64(float v) {
#pragma unroll
  for (int m = 1; m < 64; m <<= 1) v += __shfl_xor(v, m);
  return v;
}

// ---------------- Kernel 1a: q[b,:] = Wq @ x[b,0,:] + bq ----------------
__global__ __launch_bounds__(256) void k1a_q(const float* __restrict__ x,
                                             const float* __restrict__ w,
                                             const float* __restrict__ bias,
                                             float* __restrict__ q) {
  int b = blockIdx.x >> 3, blk = blockIdx.x & 7;
  int tid = threadIdx.x;
  __shared__ float x0[cE];
  ((float4*)x0)[tid] = ((const float4*)(x + (size_t)b * cS * cE))[tid];
  __syncthreads();
  int row = blk * 128 + (tid >> 1);
  int half = tid & 1;
  const float* wr = w + (size_t)row * cE + half * 512;
  const float* xl = x0 + half * 512;
  float acc = 0.f;
#pragma unroll 4
  for (int j = 0; j < 128; ++j) {
    float4 a = *(const float4*)(wr + j * 4);
    float4 xv = *(const float4*)(xl + j * 4);
    acc = fmaf(a.x, xv.x, acc); acc = fmaf(a.y, xv.y, acc);
    acc = fmaf(a.z, xv.z, acc); acc = fmaf(a.w, xv.w, acc);
  }
  float tot = acc + __shfl_xor(acc, 1);
  if (!half) q[b * cE + row] = tot + bias[row];
}

// ---------------- Kernel 1b: p[b,h,e] = 0.125 * sum_d Wk[h*64+d, e] q[b, h*64+d] ------
// grid 256 = 32 b x 4 e-chunks x 2 h-halves.
__global__ __launch_bounds__(256) void k1b_p(const float* __restrict__ w,
                                             const float* __restrict__ bvec,
                                             const float* __restrict__ q,
                                             float* __restrict__ p,
                                             float* __restrict__ cb) {
  int b = blockIdx.x >> 3, sub = blockIdx.x & 7;
  int ec = sub >> 1, hh = sub & 1;
  int tid = threadIdx.x;
  int e = ec * 256 + tid;
  __shared__ float ql[cE];
  ((float4*)ql)[tid] = ((const float4*)(q + (size_t)b * cE))[tid];
  __syncthreads();
  for (int hi = 0; hi < 8; ++hi) {
    int h = hh * 8 + hi;
    float acc = 0.f;
    const float* wb = w + (size_t)(cE + h * cD) * cE + e;
    const float* qh = ql + h * cD;
#pragma unroll 8
    for (int d = 0; d < cD; ++d) acc = fmaf(wb[(size_t)d * cE], qh[d], acc);
    p[(size_t)(b * cH + h) * cE + e] = 0.125f * acc;
  }
  if (ec == 0 && tid < 8) {
    int h = hh * 8 + tid;
    float cacc = 0.f;
    for (int d = 0; d < cD; ++d) cacc = fmaf(ql[h * cD + d], bvec[cE + h * cD + d], cacc);
    cb[b * cH + h] = 0.125f * cacc;
  }
}

// ---------------- Kernel 2: scores + mask + per-chunk softmax stats ----------------
// grid 512 = B*16 s-chunks of 256, block 256 (64 s-threads x 4 h-waves, tile 4s x 4h).
// x double-buffered in LDS (swizzled); p read via wave-uniform scalar loads (no LDS).
__global__ __launch_bounds__(256) void k2_scores(const float* __restrict__ x,
                                                 const float* __restrict__ p,
                                                 const float* __restrict__ cbias,
                                                 const int* __restrict__ mask,
                                                 float* __restrict__ scores,
                                                 float* __restrict__ statsM,
                                                 float* __restrict__ statsL) {
  __shared__ float xT[2][32 * 256];   // [buf][e][swizzled s], 2x32 KB
  int bx = blockIdx.x;
  int b = bx >> 4, sc = bx & 15;
  int s_base = sc * 256;
  int tid = threadIdx.x;
  int s_t = tid & 63, h_t = tid >> 6;
  int h0 = __builtin_amdgcn_readfirstlane(h_t * 4);   // wave-uniform -> p loads scalarize
  float acc[4][4];
#pragma unroll
  for (int i = 0; i < 4; ++i)
#pragma unroll
    for (int j = 0; j < 4; ++j) acc[i][j] = 0.f;

  const float* xb = x + ((size_t)b * cS + s_base) * cE;
  const float* __restrict__ pu = p + (size_t)(b * cH + h0) * cE;

  float4 sv[8];
  int r_ = tid >> 3, c4_ = tid & 7;

  // prologue: stage kt=0
#pragma unroll
  for (int i = 0; i < 8; ++i)
    sv[i] = *(const float4*)(xb + (size_t)(i * 32 + r_) * cE + c4_ * 4);
  {
    float* xd = xT[0];
#pragma unroll
    for (int i = 0; i < 8; ++i) {
      int r = i * 32 + r_;
      float vv[4] = {sv[i].x, sv[i].y, sv[i].z, sv[i].w};
#pragma unroll
      for (int j = 0; j < 4; ++j) {
        int e = c4_ * 4 + j;
        int f = (e ^ (e >> 4)) & 15;
        xd[e * 256 + ((((r >> 2) ^ f) << 2) | (r & 3))] = vv[j];
      }
    }
  }
  __syncthreads();

  for (int kt = 1; kt <= 32; ++kt) {
    if (kt < 32) {
#pragma unroll
      for (int i = 0; i < 8; ++i)
        sv[i] = *(const float4*)(xb + (size_t)(i * 32 + r_) * cE + kt * 32 + c4_ * 4);
    }
    {
      const float* xs = xT[(kt - 1) & 1];
      const int kb = (kt - 1) * 32;
#pragma unroll 8
      for (int e = 0; e < 32; ++e) {
        int f = (e ^ (e >> 4)) & 15;
        float4 xv = *(const float4*)&xs[e * 256 + ((s_t ^ f) << 2)];
        float p0 = pu[kb + e];
        float p1 = pu[cE + kb + e];
        float p2 = pu[2 * cE + kb + e];
        float p3 = pu[3 * cE + kb + e];
        float xa[4] = {xv.x, xv.y, xv.z, xv.w};
        float pa[4] = {p0, p1, p2, p3};
#pragma unroll
        for (int si = 0; si < 4; ++si)
#pragma unroll
          for (int hj = 0; hj < 4; ++hj) acc[si][hj] = fmaf(xa[si], pa[hj], acc[si][hj]);
      }
    }
    if (kt < 32) {
      float* xd = xT[kt & 1];
#pragma unroll
      for (int i = 0; i < 8; ++i) {
        int r = i * 32 + r_;
        float vv[4] = {sv[i].x, sv[i].y, sv[i].z, sv[i].w};
#pragma unroll
        for (int j = 0; j < 4; ++j) {
          int e = c4_ * 4 + j;
          int f = (e ^ (e >> 4)) & 15;
          xd[e * 256 + ((((r >> 2) ^ f) << 2) | (r & 3))] = vv[j];
        }
      }
    }
    __syncthreads();
  }

  // epilogue: bias, mask, store masked scores, per-chunk (max, expsum) stats
  float4 cv = *(const float4*)(cbias + b * cH + h0);
  float ca[4] = {cv.x, cv.y, cv.z, cv.w};
  int4 m4 = *(const int4*)(mask + (size_t)b * cS + s_base + s_t * 4);
#pragma unroll
  for (int hj = 0; hj < 4; ++hj) {
    float v0 = m4.x ? -1e30f : acc[0][hj] + ca[hj];
    float v1 = m4.y ? -1e30f : acc[1][hj] + ca[hj];
    float v2 = m4.z ? -1e30f : acc[2][hj] + ca[hj];
    float v3 = m4.w ? -1e30f : acc[3][hj] + ca[hj];
    *(float4*)(scores + (size_t)(b * cH + h0 + hj) * cS + s_base + s_t * 4) =
        make_float4(v0, v1, v2, v3);
    float mx = fmaxf(fmaxf(v0, v1), fmaxf(v2, v3));
    float wm = wave_max64(mx);
    float es = __expf(v0 - wm) + __expf(v1 - wm) + __expf(v2 - wm) + __expf(v3 - wm);
    float wsum = wave_sum64(es);
    if (s_t == 0) {
      statsM[(size_t)(b * cH + h0 + hj) * cNC + sc] = wm;
      statsL[(size_t)(b * cH + h0 + hj) * cNC + sc] = wsum;
    }
  }
}

// ---------------- Kernel 3t: reduce chunk stats -> M[b,h], invL[b,h] ----------------
__global__ __launch_bounds__(64) void k3t_stats(const float* __restrict__ statsM,
                                                const float* __restrict__ statsL,
                                                float* __restrict__ Mf,
                                                float* __restrict__ iLf) {
  int bh = blockIdx.x * 64 + threadIdx.x;   // 512 = B*H
  const float* sm = statsM + (size_t)bh * cNC;
  const float* sl = statsL + (size_t)bh * cNC;
  float M = -3e38f;
#pragma unroll
  for (int c = 0; c < cNC; ++c) M = fmaxf(M, sm[c]);
  float L = 0.f;
#pragma unroll
  for (int c = 0; c < cNC; ++c) L += sl[c] * __expf(sm[c] - M);
  Mf[bh] = M;
  iLf[bh] = 1.0f / L;
}

// ---------------- Kernel 4: exp-normalize + weighted sum + attn-mean ----------------
// grid 512 = B*16 s-chunks, block 256; thread owns 4 e x 16 h.
// attn for a 64-s group staged into LDS with lane-parallel exp (wave w does h=4w..4w+3),
// consumed via broadcast LDS reads. Double-buffered.
__global__ __launch_bounds__(256) void k4_wsum(const float* __restrict__ x,
                                               const float* __restrict__ scores,
                                               const float* __restrict__ Mf,
                                               const float* __restrict__ iLf,
                                               float* __restrict__ part,
                                               float* __restrict__ out) {
  __shared__ float al[2][cH][64];
  int bx = blockIdx.x;
  int b = bx >> 4, sc = bx & 15;
  int tid = threadIdx.x;
  int wv = tid >> 6, lane = tid & 63;
  int e0 = tid * 4;
  const float* xb = x + ((size_t)b * cS + sc * 256) * cE + e0;
  const float* sb = scores + (size_t)b * cH * cS + sc * 256;

  float4 acc[16];
#pragma unroll
  for (int h = 0; h < cH; ++h) acc[h] = make_float4(0.f, 0.f, 0.f, 0.f);

  // stage group 0
#pragma unroll
  for (int j = 0; j < 4; ++j) {
    int h = wv * 4 + j;
    float Mh = Mf[b * cH + h];
    float iLh = iLf[b * cH + h];
    float v = sb[(size_t)h * cS + lane];
    al[0][h][lane] = __expf(v - Mh) * iLh;
  }
  __syncthreads();

  for (int g = 0; g < 4; ++g) {
    if (g < 3) {
#pragma unroll
      for (int j = 0; j < 4; ++j) {
        int h = wv * 4 + j;
        float Mh = Mf[b * cH + h];
        float iLh = iLf[b * cH + h];
        float v = sb[(size_t)h * cS + (g + 1) * 64 + lane];
        al[(g + 1) & 1][h][lane] = __expf(v - Mh) * iLh;
      }
    }
    const float (*ab)[64] = al[g & 1];
    const float* xg = xb + (size_t)(g * 64) * cE;
#pragma unroll 4
    for (int s = 0; s < 64; ++s) {
      float4 xv = *(const float4*)(xg + (size_t)s * cE);
      float aa[16];
#pragma unroll
      for (int h = 0; h < cH; ++h) aa[h] = ab[h][s];
#pragma unroll
      for (int h = 0; h < cH; ++h) {
        acc[h].x = fmaf(aa[h], xv.x, acc[h].x);
        acc[h].y = fmaf(aa[h], xv.y, acc[h].y);
        acc[h].z = fmaf(aa[h], xv.z, acc[h].z);
        acc[h].w = fmaf(aa[h], xv.w, acc[h].w);
      }
    }
    // attn-weights mean for this group (one wave, round-robin)
    if (wv == g) {
      float ms = 0.f;
#pragma unroll
      for (int h = 0; h < cH; ++h) ms += ab[h][lane];
      out[cB * cE + (size_t)b * cS + sc * 256 + g * 64 + lane] = ms * (1.0f / 16.0f);
    }
    __syncthreads();
  }

  float* pb = part + ((size_t)(b * cNC + sc) * cH) * cE + e0;
#pragma unroll
  for (int h = 0; h < cH; ++h) *(float4*)(pb + (size_t)h * cE) = acc[h];
}

// ---------------- Kernel 5: y = sum_sc part; ctx[b,h*64+d] = Wv_h[d,:].y + bv ----------
__global__ __launch_bounds__(256) void k5_ctx(const float* __restrict__ w,
                                              const float* __restrict__ bvec,
                                              const float* __restrict__ part,
                                              float* __restrict__ ctx) {
  int b = blockIdx.x >> 4, h = blockIdx.x & 15;
  int tid = threadIdx.x;
  __shared__ float yl[cE];
  float4 a = make_float4(0.f, 0.f, 0.f, 0.f);
  const float* pb = part + ((size_t)(b * cNC) * cH + h) * cE + tid * 4;
#pragma unroll
  for (int s = 0; s < cNC; ++s) {
    float4 v = *(const float4*)(pb + (size_t)s * cH * cE);
    a.x += v.x; a.y += v.y; a.z += v.z; a.w += v.w;
  }
  *(float4*)(yl + tid * 4) = a;
  __syncthreads();
  int wid = tid >> 6, lane = tid & 63;
  for (int i = 0; i < 16; ++i) {
    int d = wid * 16 + i;
    const float* wr = w + (size_t)(2 * cE + h * cD + d) * cE + lane * 16;
    const float* yr = yl + lane * 16;
    float partial = 0.f;
#pragma unroll
    for (int j = 0; j < 4; ++j) {
      float4 wvv = *(const float4*)(wr + j * 4);
      float4 yv = *(const float4*)(yr + j * 4);
      partial = fmaf(wvv.x, yv.x, partial); partial = fmaf(wvv.y, yv.y, partial);
      partial = fmaf(wvv.z, yv.z, partial); partial = fmaf(wvv.w, yv.w, partial);
    }
    partial = wave_sum64(partial);
    if (lane == 0) ctx[b * cE + h * cD + d] = partial + bvec[2 * cE + h * cD + d];
  }
}

// ---------------- Kernel 6: out[b,:] = out_w @ ctx[b,:] + out_b ----------------
__global__ __launch_bounds__(256) void k6_out(const float* __restrict__ w,
                                              const float* __restrict__ bvec,
                                              const float* __restrict__ ctx,
                                              float* __restrict__ out) {
  int b = blockIdx.x >> 3, br = blockIdx.x & 7;
  int tid = threadIdx.x;
  __shared__ float cl[cE];
  ((float4*)cl)[tid] = ((const float4*)(ctx + (size_t)b * cE))[tid];
  __syncthreads();
  int wid = tid >> 6, lane = tid & 63;
  for (int i = 0; i < 32; ++i) {
    int row = br * 128 + wid * 32 + i;
    const float* wr = w + (size_t)row * cE + lane * 16;
    const float* cr = cl + lane * 16;
    float partial = 0.f;
#pragma unroll
    for (int j = 0; j < 4; ++j) {
      float4 wvv = *(const float4*)(wr + j * 4);
      float4 cvv = *(const float4*)(cr + j * 4);
      partial = fmaf(wvv.x, cvv.x, partial); partial = fmaf(wvv.y, cvv.y, partial);
      partial = fmaf(wvv.z, cvv.z, partial); partial = fmaf(wvv.w, cvv.w, partial);
    }
    partial = wave_sum64(partial);
    if (lane == 0) out[(size_t)b * cE + row] = partial + bvec[row];
  }
}

extern "C" void kernel_launch(void* const* d_in, const int* in_sizes, int n_in,
                              void* d_out, int out_size, void* d_ws, size_t ws_size,
                              hipStream_t stream) {
  const float* x = (const float*)d_in[0];
  const int* mask = (const int*)d_in[1];
  const float* in_proj_w = (const float*)d_in[2];
  const float* in_proj_b = (const float*)d_in[3];
  const float* out_w = (const float*)d_in[4];
  const float* out_b = (const float*)d_in[5];
  float* out = (float*)d_out;
  float* W = (float*)d_ws;

  float* p = W + OFF_P;
  float* cb = W + OFF_C;
  float* q = W + OFF_Q;
  float* scores = W + OFF_SC;
  float* ctx = W + OFF_CTX;
  float* statsM = W + OFF_SM;
  float* statsL = W + OFF_SL;
  float* Mf = W + OFF_MF;
  float* iLf = W + OFF_IL;
  float* part = W + OFF_PART;

  k1a_q<<<256, 256, 0, stream>>>(x, in_proj_w, in_proj_b, q);
  k1b_p<<<256, 256, 0, stream>>>(in_proj_w, in_proj_b, q, p, cb);
  k2_scores<<<512, 256, 0, stream>>>(x, p, cb, mask, scores, statsM, statsL);
  k3t_stats<<<8, 64, 0, stream>>>(statsM, statsL, Mf, iLf);
  k4_wsum<<<512, 256, 0, stream>>>(x, scores, Mf, iLf, part, out);
  k5_ctx<<<512, 256, 0, stream>>>(in_proj_w, in_proj_b, part, ctx);
  k6_out<<<256, 256, 0, stream>>>(out_w, out_b, ctx, out);
}